// Round 3
// baseline (801.617 us; speedup 1.0000x reference)
//
#include <hip/hip_runtime.h>

// Adding-doubling radiative transfer: B=2048 cols, N=60 layers, C=128 channels.
// One thread per (b,c) column; all layer recurrences serial per thread.
//
// R3 changes vs R2 (VGPR=64 + arr[] spilled to scratch: 1.26 GB HBM traffic,
// 2.9x ideal, 451us):
//   * arr[60] moved to LDS, layout [NL][256]: lane i -> bank i%32 at uniform l,
//     2 lanes/bank = conflict-free. 60 KiB/block -> 2 blocks/CU (8 waves/CU).
//     Deterministic on-chip storage; zero scratch traffic.
//   * __launch_bounds__(256, 2): VGPR cap 256 (matches LDS-limited occupancy);
//     frees the allocator to hoist loads deep across the unrolled layer loops,
//     which is what actually hides HBM latency at 8 waves/CU.
// Kept: single array (rt overwrites rs in place), absorbed down-part written in
// phase B, += up-part in phase C (same-thread RMW), fast rcp.

#define NL 60
#define CC 128
#define TPB 256

__device__ __forceinline__ float frcp(float x) {
    return __builtin_amdgcn_rcpf(x);
}

__global__ __launch_bounds__(TPB, 2) void adding_doubling_kernel(
    const float* __restrict__ a, const float* __restrict__ r,
    const float* __restrict__ t, const float* __restrict__ s,
    float* __restrict__ flux_down, float* __restrict__ flux_up,
    float* __restrict__ absorbed, int ncol)
{
    // phase A: rs[l]; phase B onwards: rt[l] (in-place overwrite).
    // Each thread touches only column threadIdx.x -> no syncs needed.
    __shared__ float arr[NL][TPB];

    const int tid = blockIdx.x * blockDim.x + threadIdx.x;
    if (tid >= ncol) return;
    const int tx = threadIdx.x;
    const int b = tid >> 7;          // tid / CC
    const int c = tid & (CC - 1);    // tid % CC
    const int base = b * NL * CC + c;   // element (b, l=0, c); layer l at base + l*CC

    // ---------------- Phase A: bottom-up cumulative surface reflection ----
    // rs[n-1] = r[n-1]; for l=n-2..0: dd = 1/(1-rs[l+1]*r[l]);
    // rs[l] = r[l] + rs[l+1]*t[l]^2*dd.
    {
        float rs_next = r[base + (NL - 1) * CC];
        arr[NL - 1][tx] = rs_next;
        #pragma unroll
        for (int l = NL - 2; l >= 0; --l) {
            float rl = r[base + l * CC];
            float tl = t[base + l * CC];
            float dd = frcp(1.0f - rs_next * rl);
            rs_next = rl + rs_next * tl * tl * dd;
            arr[l][tx] = rs_next;
        }
    }

    // ---------------- Phase B: forward pass ------------------------------
    // Downward flux scan (consumes rs = arr[m+1]), flux_down writes,
    // absorbed down-contribution written straight to global, and the
    // top-down reflection recurrence rt[m] overwriting arr[m] in place.
    {
        float r_prev = r[base];        // r[m-1]
        float s_prev = s[base];        // s[m-1]
        float ds_prev = frcp(1.0f - arr[1][tx] * r_prev);   // ds[0]  (arr[1]=rs[1])
        float rt_prev = r_prev;        // rt[0]
        arr[0][tx] = r_prev;           // rt[0] overwrites rs[0] (rs[0] never read)
        float flux = 0.0f;
        #pragma unroll
        for (int m = 1; m < NL; ++m) {
            float rm = r[base + m * CC];
            float sm = s[base + m * CC];
            float tm = t[base + m * CC];
            float am = a[base + m * CC];
            // downward flux: add s_down[m-1] = (s[m-1] + s[m]*r[m-1]) * ds[m-1]
            flux += (s_prev + sm * r_prev) * ds_prev;
            flux_down[base + m * CC] = flux;
            if (m < NL - 1) {
                float rs_m1 = arr[m + 1][tx];               // rs[m+1]
                float ds_m = frcp(1.0f - rs_m1 * rm);       // ds[m]
                // absorbed_down[m] -> global (up part added in phase C)
                absorbed[base + m * CC] = am * (1.0f + rs_m1 * tm * ds_m) * flux;
                flux *= tm * ds_m;
                ds_prev = ds_m;
            } else {
                // layer n-1: absorbed_up is 0 there, final value now
                absorbed[base + m * CC] = am * flux;
            }
            // top-down reflection recurrence; rt[m] overwrites rs[m] (dead)
            float dt_m = frcp(1.0f - rt_prev * rm);
            float rt_m = rm + rt_prev * tm * tm * dt_m;
            if (m < NL - 1) arr[m][tx] = rt_m;
            rt_prev = rt_m;
            r_prev = rm;
            s_prev = sm;
        }
        flux_down[base] = 0.0f;   // flux_down[0] = 0
    }

    // ---------------- Phase C: reverse pass (upward flux) -----------------
    // dt[l] = 1/(1 - rt[l-1]*r[l]) recomputed from arr (=rt) and r.
    // absorbed[l] += up-contribution (reads phase-B write, same thread).
    {
        float flux = 0.0f;
        float r_hi = r[base + (NL - 1) * CC];   // r[k+2]
        float s_hi = s[base + (NL - 1) * CC];   // s[k+2]
        float dt_hi = frcp(1.0f - arr[NL - 2][tx] * r_hi);   // dt[n-1]
        #pragma unroll
        for (int k = NL - 3; k >= 0; --k) {
            float r1 = r[base + (k + 1) * CC];
            float s1 = s[base + (k + 1) * CC];
            float t1 = t[base + (k + 1) * CC];
            float a1 = a[base + (k + 1) * CC];
            // flux += s_up[k+2]
            flux += (s_hi + s1 * r_hi) * dt_hi;
            flux_up[base + (k + 2) * CC] = flux;
            float rt_k = arr[k][tx];                 // rt[k]
            float dt1 = frcp(1.0f - rt_k * r1);      // dt[k+1]
            absorbed[base + (k + 1) * CC] +=
                flux * a1 * (1.0f + t1 * rt_k * dt1);
            flux *= t1 * dt1;
            r_hi = r1;
            s_hi = s1;
            dt_hi = dt1;
        }
        // tail: after k=0 iter, r_hi=r[1], s_hi=s[1], dt_hi=dt[1]
        float r0v = r[base];
        float s0v = s[base];
        float t0v = t[base];
        float a0v = a[base];
        float flux1 = flux + (s_hi + s0v * r_hi) * dt_hi;   // + s_up[1]
        flux_up[base + CC] = flux1;
        absorbed[base] = flux1 * a0v;                        // abs1 (down part = 0)
        flux_up[base] = flux1 * t0v + s0v;                   // flux1*t[0] + s_up[0]
    }
}

extern "C" void kernel_launch(void* const* d_in, const int* in_sizes, int n_in,
                              void* d_out, int out_size, void* d_ws, size_t ws_size,
                              hipStream_t stream) {
    const float* a = (const float*)d_in[0];
    const float* r = (const float*)d_in[1];
    const float* t = (const float*)d_in[2];
    const float* s = (const float*)d_in[3];
    const int total = in_sizes[0];       // B*N*C
    const int ncol = total / NL;         // B*C columns
    float* flux_down = (float*)d_out;
    float* flux_up = flux_down + total;
    float* absorbed = flux_up + total;
    const int threads = TPB;
    const int blocks = (ncol + threads - 1) / threads;
    adding_doubling_kernel<<<blocks, threads, 0, stream>>>(
        a, r, t, s, flux_down, flux_up, absorbed, ncol);
}

// Round 5
// 430.933 us; speedup vs baseline: 1.8602x; 1.8602x over previous
//
#include <hip/hip_runtime.h>

// Adding-doubling radiative transfer: B=2048 cols, N=60 layers, C=128 channels.
// One thread per (b,c) column; all layer recurrences serial per thread.
//
// R4 changes vs R3 (VGPR=128 but ~470 MiB of spill WRITES from full-unroll
// load hoisting; 1.31 GB HBM traffic; 570us):
//   * #pragma unroll 4 on all layer loops: bounds the compiler's hoisting
//     window (~16 loads in flight = enough ILP), register pressure drops to
//     spill-free levels naturally. R1-R3 showed full unroll = spill generator
//     at ANY register budget.
//   * Block 128: 30 KiB LDS/block -> 5 blocks/CU = 10 waves/CU resident
//     (vs 8 at block 256), finer scheduling granularity.
//   * No min-waves launch bound (R2: hard VGPR caps make the allocator dump
//     arrays to scratch).
// Kept: arr[] in LDS [NL][TPB] (2 lanes/bank = conflict-free), rt overwrites
// rs in place, absorbed down-part in phase B + RMW up-part in phase C, fast rcp.

#define NL 60
#define CC 128
#define TPB 128

__device__ __forceinline__ float frcp(float x) {
    return __builtin_amdgcn_rcpf(x);
}

__global__ __launch_bounds__(TPB) void adding_doubling_kernel(
    const float* __restrict__ a, const float* __restrict__ r,
    const float* __restrict__ t, const float* __restrict__ s,
    float* __restrict__ flux_down, float* __restrict__ flux_up,
    float* __restrict__ absorbed, int ncol)
{
    // phase A: rs[l]; phase B onwards: rt[l] (in-place overwrite).
    // Each thread touches only column threadIdx.x -> no syncs needed.
    __shared__ float arr[NL][TPB];

    const int tid = blockIdx.x * blockDim.x + threadIdx.x;
    if (tid >= ncol) return;
    const int tx = threadIdx.x;
    const int b = tid >> 7;          // tid / CC
    const int c = tid & (CC - 1);    // tid % CC
    const int base = b * NL * CC + c;   // element (b, l=0, c); layer l at base + l*CC

    // ---------------- Phase A: bottom-up cumulative surface reflection ----
    // rs[n-1] = r[n-1]; for l=n-2..0: dd = 1/(1-rs[l+1]*r[l]);
    // rs[l] = r[l] + rs[l+1]*t[l]^2*dd.
    {
        float rs_next = r[base + (NL - 1) * CC];
        arr[NL - 1][tx] = rs_next;
        #pragma unroll 4
        for (int l = NL - 2; l >= 0; --l) {
            float rl = r[base + l * CC];
            float tl = t[base + l * CC];
            float dd = frcp(1.0f - rs_next * rl);
            rs_next = rl + rs_next * tl * tl * dd;
            arr[l][tx] = rs_next;
        }
    }

    // ---------------- Phase B: forward pass ------------------------------
    // Downward flux scan (consumes rs = arr[m+1]), flux_down writes,
    // absorbed down-contribution written straight to global, and the
    // top-down reflection recurrence rt[m] overwriting arr[m] in place.
    {
        float r_prev = r[base];        // r[m-1]
        float s_prev = s[base];        // s[m-1]
        float ds_prev = frcp(1.0f - arr[1][tx] * r_prev);   // ds[0]  (arr[1]=rs[1])
        float rt_prev = r_prev;        // rt[0]
        arr[0][tx] = r_prev;           // rt[0] overwrites rs[0] (rs[0] never read)
        float flux = 0.0f;
        #pragma unroll 4
        for (int m = 1; m < NL; ++m) {
            float rm = r[base + m * CC];
            float sm = s[base + m * CC];
            float tm = t[base + m * CC];
            float am = a[base + m * CC];
            // downward flux: add s_down[m-1] = (s[m-1] + s[m]*r[m-1]) * ds[m-1]
            flux += (s_prev + sm * r_prev) * ds_prev;
            flux_down[base + m * CC] = flux;
            if (m < NL - 1) {
                float rs_m1 = arr[m + 1][tx];               // rs[m+1]
                float ds_m = frcp(1.0f - rs_m1 * rm);       // ds[m]
                // absorbed_down[m] -> global (up part added in phase C)
                absorbed[base + m * CC] = am * (1.0f + rs_m1 * tm * ds_m) * flux;
                flux *= tm * ds_m;
                ds_prev = ds_m;
            } else {
                // layer n-1: absorbed_up is 0 there, final value now
                absorbed[base + m * CC] = am * flux;
            }
            // top-down reflection recurrence; rt[m] overwrites rs[m] (dead)
            float dt_m = frcp(1.0f - rt_prev * rm);
            float rt_m = rm + rt_prev * tm * tm * dt_m;
            if (m < NL - 1) arr[m][tx] = rt_m;
            rt_prev = rt_m;
            r_prev = rm;
            s_prev = sm;
        }
        flux_down[base] = 0.0f;   // flux_down[0] = 0
    }

    // ---------------- Phase C: reverse pass (upward flux) -----------------
    // dt[l] = 1/(1 - rt[l-1]*r[l]) recomputed from arr (=rt) and r.
    // absorbed[l] += up-contribution (reads phase-B write, same thread).
    {
        float flux = 0.0f;
        float r_hi = r[base + (NL - 1) * CC];   // r[k+2]
        float s_hi = s[base + (NL - 1) * CC];   // s[k+2]
        float dt_hi = frcp(1.0f - arr[NL - 2][tx] * r_hi);   // dt[n-1]
        #pragma unroll 4
        for (int k = NL - 3; k >= 0; --k) {
            float r1 = r[base + (k + 1) * CC];
            float s1 = s[base + (k + 1) * CC];
            float t1 = t[base + (k + 1) * CC];
            float a1 = a[base + (k + 1) * CC];
            // flux += s_up[k+2]
            flux += (s_hi + s1 * r_hi) * dt_hi;
            flux_up[base + (k + 2) * CC] = flux;
            float rt_k = arr[k][tx];                 // rt[k]
            float dt1 = frcp(1.0f - rt_k * r1);      // dt[k+1]
            absorbed[base + (k + 1) * CC] +=
                flux * a1 * (1.0f + t1 * rt_k * dt1);
            flux *= t1 * dt1;
            r_hi = r1;
            s_hi = s1;
            dt_hi = dt1;
        }
        // tail: after k=0 iter, r_hi=r[1], s_hi=s[1], dt_hi=dt[1]
        float r0v = r[base];
        float s0v = s[base];
        float t0v = t[base];
        float a0v = a[base];
        float flux1 = flux + (s_hi + s0v * r_hi) * dt_hi;   // + s_up[1]
        flux_up[base + CC] = flux1;
        absorbed[base] = flux1 * a0v;                        // abs1 (down part = 0)
        flux_up[base] = flux1 * t0v + s0v;                   // flux1*t[0] + s_up[0]
    }
}

extern "C" void kernel_launch(void* const* d_in, const int* in_sizes, int n_in,
                              void* d_out, int out_size, void* d_ws, size_t ws_size,
                              hipStream_t stream) {
    const float* a = (const float*)d_in[0];
    const float* r = (const float*)d_in[1];
    const float* t = (const float*)d_in[2];
    const float* s = (const float*)d_in[3];
    const int total = in_sizes[0];       // B*N*C
    const int ncol = total / NL;         // B*C columns
    float* flux_down = (float*)d_out;
    float* flux_up = flux_down + total;
    float* absorbed = flux_up + total;
    const int threads = TPB;
    const int blocks = (ncol + threads - 1) / threads;
    adding_doubling_kernel<<<blocks, threads, 0, stream>>>(
        a, r, t, s, flux_down, flux_up, absorbed, ncol);
}

// Round 6
// 401.870 us; speedup vs baseline: 1.9947x; 1.0723x over previous
//
#include <hip/hip_runtime.h>

// Adding-doubling radiative transfer: B=2048 cols, N=60 layers, C=128 channels.
// One thread per (b,c) column; all layer recurrences serial per thread.
//
// R6 changes vs R5 (194us, hbm 565MB = 440 compulsory + 126 absorbed-RMW
// round-trip, 2.9 TB/s, VALUBusy 11%):
//   * absorbed RMW eliminated: phase C recomputes rs as a running scalar
//     (its bottom-up recurrence matches C's traversal direction), re-reads
//     flux_down (our own output, replaces the absorbed re-read) and writes
//     absorbed exactly once. Phase B no longer loads a[] nor writes absorbed
//     (except the trivial last layer). -51 MiB HBM writes.
//   * #pragma unroll 8 (was 4): doubles loads in flight between the serial
//     rcp-chain groups -> attacks the 2.9/6.3 TB/s latency gap. VGPR
//     predicted ~110-150, below the spill cliff (watch WRITE_SIZE).
// Kept: arr[] in LDS [NL][TPB] (conflict-free), rt overwrites rs in place,
// block=128 (30 KiB LDS -> 5 blocks/CU), fast rcp, no min-wave bound.

#define NL 60
#define CC 128
#define TPB 128

__device__ __forceinline__ float frcp(float x) {
    return __builtin_amdgcn_rcpf(x);
}

__global__ __launch_bounds__(TPB) void adding_doubling_kernel(
    const float* __restrict__ a, const float* __restrict__ r,
    const float* __restrict__ t, const float* __restrict__ s,
    float* __restrict__ flux_down, float* __restrict__ flux_up,
    float* __restrict__ absorbed, int ncol)
{
    // phase A: rs[l]; phase B onwards: rt[l] (in-place overwrite).
    // Each thread touches only column threadIdx.x -> no syncs needed.
    __shared__ float arr[NL][TPB];

    const int tid = blockIdx.x * blockDim.x + threadIdx.x;
    if (tid >= ncol) return;
    const int tx = threadIdx.x;
    const int b = tid >> 7;          // tid / CC
    const int c = tid & (CC - 1);    // tid % CC
    const int base = b * NL * CC + c;   // element (b, l=0, c); layer l at base + l*CC

    // ---------------- Phase A: bottom-up cumulative surface reflection ----
    // rs[n-1] = r[n-1]; for l=n-2..0: dd = 1/(1-rs[l+1]*r[l]);
    // rs[l] = r[l] + rs[l+1]*t[l]^2*dd.
    {
        float rs_next = r[base + (NL - 1) * CC];
        arr[NL - 1][tx] = rs_next;
        #pragma unroll 8
        for (int l = NL - 2; l >= 0; --l) {
            float rl = r[base + l * CC];
            float tl = t[base + l * CC];
            float dd = frcp(1.0f - rs_next * rl);
            rs_next = rl + rs_next * tl * tl * dd;
            arr[l][tx] = rs_next;
        }
    }

    // ---------------- Phase B: forward pass ------------------------------
    // Downward flux scan (consumes rs = arr[m+1]), flux_down writes, and the
    // top-down reflection recurrence rt[m] overwriting arr[m] in place.
    // absorbed down-part is NOT computed here (recomputed in phase C).
    {
        float r_prev = r[base];        // r[m-1]
        float s_prev = s[base];        // s[m-1]
        float ds_prev = frcp(1.0f - arr[1][tx] * r_prev);   // ds[0]  (arr[1]=rs[1])
        float rt_prev = r_prev;        // rt[0]
        arr[0][tx] = r_prev;           // rt[0] overwrites rs[0] (rs[0] never read)
        float flux = 0.0f;
        #pragma unroll 8
        for (int m = 1; m < NL; ++m) {
            float rm = r[base + m * CC];
            float sm = s[base + m * CC];
            float tm = t[base + m * CC];
            // downward flux: add s_down[m-1] = (s[m-1] + s[m]*r[m-1]) * ds[m-1]
            flux += (s_prev + sm * r_prev) * ds_prev;
            flux_down[base + m * CC] = flux;
            if (m < NL - 1) {
                float rs_m1 = arr[m + 1][tx];               // rs[m+1]
                float ds_m = frcp(1.0f - rs_m1 * rm);       // ds[m]
                flux *= tm * ds_m;
                ds_prev = ds_m;
            } else {
                // layer n-1: absorbed_up = 0 and absD needs no rs -> final now
                absorbed[base + m * CC] = a[base + m * CC] * flux;
            }
            // top-down reflection recurrence; rt[m] overwrites rs[m] (dead)
            float dt_m = frcp(1.0f - rt_prev * rm);
            float rt_m = rm + rt_prev * tm * tm * dt_m;
            if (m < NL - 1) arr[m][tx] = rt_m;
            rt_prev = rt_m;
            r_prev = rm;
            s_prev = sm;
        }
        flux_down[base] = 0.0f;   // flux_down[0] = 0
    }

    // ---------------- Phase C: reverse pass (upward flux) -----------------
    // dt[l] = 1/(1 - rt[l-1]*r[l]) recomputed from arr (=rt) and r.
    // rs recomputed as a running scalar (bottom-up recurrence matches the
    // traversal direction); absorbed = down-part + up-part, written ONCE.
    {
        float flux = 0.0f;
        float r_hi = r[base + (NL - 1) * CC];   // r[k+2]
        float s_hi = s[base + (NL - 1) * CC];   // s[k+2]
        float dt_hi = frcp(1.0f - arr[NL - 2][tx] * r_hi);   // dt[n-1]
        float rs_run = r_hi;                    // rs[NL-1] = r[NL-1]
        #pragma unroll 8
        for (int k = NL - 3; k >= 0; --k) {
            // layer l = k+1
            float r1 = r[base + (k + 1) * CC];
            float s1 = s[base + (k + 1) * CC];
            float t1 = t[base + (k + 1) * CC];
            float a1 = a[base + (k + 1) * CC];
            float fd1 = flux_down[base + (k + 1) * CC];   // our phase-B write
            // flux += s_up[k+2]
            flux += (s_hi + s1 * r_hi) * dt_hi;
            flux_up[base + (k + 2) * CC] = flux;
            // down-part of absorbed at layer l, via rs_run = rs[l+1]
            float ds1 = frcp(1.0f - rs_run * r1);          // ds[l]
            float absD = a1 * (1.0f + rs_run * t1 * ds1) * fd1;
            rs_run = r1 + rs_run * t1 * t1 * ds1;          // rs[l] for next iter
            // up-part + single absorbed write
            float rt_k = arr[k][tx];                 // rt[k]
            float dt1 = frcp(1.0f - rt_k * r1);      // dt[k+1]
            absorbed[base + (k + 1) * CC] =
                absD + flux * a1 * (1.0f + t1 * rt_k * dt1);
            flux *= t1 * dt1;
            r_hi = r1;
            s_hi = s1;
            dt_hi = dt1;
        }
        // tail: after k=0 iter, r_hi=r[1], s_hi=s[1], dt_hi=dt[1]
        float r0v = r[base];
        float s0v = s[base];
        float t0v = t[base];
        float a0v = a[base];
        float flux1 = flux + (s_hi + s0v * r_hi) * dt_hi;   // + s_up[1]
        flux_up[base + CC] = flux1;
        absorbed[base] = flux1 * a0v;        // down part = 0 (flux_down[0]=0)
        flux_up[base] = flux1 * t0v + s0v;   // flux1*t[0] + s_up[0]
    }
}

extern "C" void kernel_launch(void* const* d_in, const int* in_sizes, int n_in,
                              void* d_out, int out_size, void* d_ws, size_t ws_size,
                              hipStream_t stream) {
    const float* a = (const float*)d_in[0];
    const float* r = (const float*)d_in[1];
    const float* t = (const float*)d_in[2];
    const float* s = (const float*)d_in[3];
    const int total = in_sizes[0];       // B*N*C
    const int ncol = total / NL;         // B*C columns
    float* flux_down = (float*)d_out;
    float* flux_up = flux_down + total;
    float* absorbed = flux_up + total;
    const int threads = TPB;
    const int blocks = (ncol + threads - 1) / threads;
    adding_doubling_kernel<<<blocks, threads, 0, stream>>>(
        a, r, t, s, flux_down, flux_up, absorbed, ncol);
}